// Round 8
// baseline (235.683 us; speedup 1.0000x reference)
//
#include <hip/hip_runtime.h>
#include <hip/hip_bf16.h>
#include <stdint.h>

#define BROWS 4096
#define DDIM  1024
#define LSTR  136  // fp8 LDS row stride bytes: 128 + 8 pad; measured conflict-free (R7: 0)

typedef float f32x4 __attribute__((ext_vector_type(4)));
typedef long  lx2   __attribute__((ext_vector_type(2)));
#define PSCALE 64.0f
#define INV_PSCALE 0.015625f

__device__ __forceinline__ int pack4_fp8(float a, float b, float c, float d) {
    int w = __builtin_amdgcn_cvt_pk_fp8_f32(a, b, 0, false);
    w = __builtin_amdgcn_cvt_pk_fp8_f32(c, d, w, true);
    return w;
}

// ---------------------------------------------------------------------------
// Kernel 1: prep — log(q)->fp8, (64*p)->fp8 in K-PERMUTED layout: within each
//   128-col chunk, col ks*32+q4*8+r -> q4*32+ks*8+r, so GEMM frag reads are
//   clean b128s. Also e[row], kl_div[row], zero CS/CL/EL, label bitmask.
//   (unchanged from R7 — verified absmax 0)
// ---------------------------------------------------------------------------
__global__ __launch_bounds__(256) void prep_kernel(
    const float* __restrict__ q, const float* __restrict__ p,
    const float* __restrict__ L,
    int* __restrict__ lq8, int* __restrict__ p8,
    uint64_t* __restrict__ Lb,
    float* __restrict__ e, float* __restrict__ kld,
    float* __restrict__ CS, float* __restrict__ CL, float* __restrict__ EL)
{
    const int row = blockIdx.x;
    const int t   = threadIdx.x;
    const int wv  = t >> 6, ln = t & 63;

    const float4* qv4 = (const float4*)(q + (size_t)row * DDIM);
    const float4* pv4 = (const float4*)(p + (size_t)row * DDIM);
    float4 qv = qv4[t];
    float4 pv = pv4[t];

    float lq0 = __logf(qv.x), lq1 = __logf(qv.y), lq2 = __logf(qv.z), lq3 = __logf(qv.w);
    float lp0 = __logf(pv.x), lp1 = __logf(pv.y), lp2 = __logf(pv.z), lp3 = __logf(pv.w);

    float esum = pv.x * lp0 + pv.y * lp1 + pv.z * lp2 + pv.w * lp3;
    float ksum = pv.x * (lp0 - lq0) + pv.y * (lp1 - lq1)
               + pv.z * (lp2 - lq2) + pv.w * (lp3 - lq3);

    const int c0    = t * 4;
    const int chunk = c0 >> 7;
    const int c7    = c0 & 127;
    const int ks    = (c7 >> 5) & 3;
    const int q4v   = (c7 >> 3) & 3;
    const int rr    = c7 & 7;                    // 0 or 4
    const int newc  = chunk * 128 + q4v * 32 + ks * 8 + rr;
    const int idx   = (row * DDIM + newc) >> 2;
    lq8[idx] = pack4_fp8(lq0, lq1, lq2, lq3);
    p8 [idx] = pack4_fp8(pv.x * PSCALE, pv.y * PSCALE, pv.z * PSCALE, pv.w * PSCALE);

    const float* Lrow = L + (size_t)row * BROWS;
    #pragma unroll
    for (int c = 0; c < 16; c++) {
        float v = Lrow[c * 256 + t];
        unsigned long long m = __ballot(v != 0.0f);
        if (ln == 0) Lb[(size_t)row * 64 + c * 4 + wv] = m;
    }

    if (t == 0) { CS[row] = 0.f; CL[row] = 0.f; EL[row] = 0.f; }

    #pragma unroll
    for (int off = 32; off > 0; off >>= 1) {
        esum += __shfl_down(esum, off);
        ksum += __shfl_down(ksum, off);
    }
    __shared__ float se[4], sk[4];
    if (ln == 0) { se[wv] = esum; sk[wv] = ksum; }
    __syncthreads();
    if (t == 0) {
        e[row]   = se[0] + se[1] + se[2] + se[3];
        kld[row] = (sk[0] + sk[1] + sk[2] + sk[3]) * (1.0f / DDIM);
    }
}

// ---------------------------------------------------------------------------
// Kernel 2: cross = log_q @ p^T, fp8 e4m3. Tile 128x128, 256 threads
//   (4 waves of 64x64), __launch_bounds__(256,3): reg cap 170 >= demand ~145
//   -> NO scratch spill (R7's 208 MB WRITE_SIZE was spill at cap 128).
//   3 blocks/CU co-resident; BK=128 B chunks (8 chunks, 2 barriers each);
//   1-deep register prefetch; LSTR=136 conflict-free (measured R7).
// ---------------------------------------------------------------------------
__global__ __launch_bounds__(256, 3) void gemm_epi_kernel(
    const uint8_t* __restrict__ A8,   // fp8 log_q [B,D] K-permuted
    const uint8_t* __restrict__ B8,   // fp8 64*p  [B,D] K-permuted
    const uint64_t* __restrict__ Lb,  // [B, B/64] bitmask
    const float*  __restrict__ e,     // [B]
    float* __restrict__ CS, float* __restrict__ CL, float* __restrict__ EL)
{
    __shared__ __align__(16) uint8_t As[128 * LSTR];  // 17 KB
    __shared__ __align__(16) uint8_t Bs[128 * LSTR];  // 17 KB

    const int t    = threadIdx.x;
    const int i0   = blockIdx.y * 128;
    const int j0   = blockIdx.x * 128;
    const int wave = t >> 6;
    const int lane = t & 63;
    const int q4   = lane >> 4;
    const int ln   = lane & 15;
    const int wrow = wave >> 1;   // 2 i-subtiles of 64
    const int wcol = wave & 1;    // 2 j-subtiles of 64

    f32x4 acc[4][4];
    #pragma unroll
    for (int a = 0; a < 4; a++)
        #pragma unroll
        for (int b = 0; b < 4; b++)
            acc[a][b] = (f32x4){0.f, 0.f, 0.f, 0.f};

    // staging: each tile chunk = 128 rows x 128 B = 1024 16B units; 4/thread
    const uint8_t* gA[4]; const uint8_t* gB[4]; int lofs[4];
    #pragma unroll
    for (int n = 0; n < 4; n++) {
        const int u = t + n * 256;
        const int r = u >> 3, cb = (u & 7) * 16;
        gA[n] = A8 + (size_t)(i0 + r) * DDIM + cb;
        gB[n] = B8 + (size_t)(j0 + r) * DDIM + cb;
        lofs[n] = r * LSTR + cb;
    }

    int4 pfA[4], pfB[4];
    #pragma unroll
    for (int n = 0; n < 4; n++) { pfA[n] = *(const int4*)(gA[n]); pfB[n] = *(const int4*)(gB[n]); }

    #pragma unroll 1
    for (int c = 0; c < DDIM / 128; ++c) {
        __syncthreads();                 // prior chunk's readers done
        #pragma unroll
        for (int n = 0; n < 4; n++) {
            *(int4*)(As + lofs[n]) = pfA[n];
            *(int4*)(Bs + lofs[n]) = pfB[n];
        }
        __syncthreads();                 // chunk c visible

        if (c + 1 < DDIM / 128) {
            const int k = (c + 1) * 128;
            #pragma unroll
            for (int n = 0; n < 4; n++) {
                pfA[n] = *(const int4*)(gA[n] + k);
                pfB[n] = *(const int4*)(gB[n] + k);
            }
        }

        // pass 0 = ks0,ks1 (bytes q4*32 .. +16), pass 1 = ks2,ks3 (+16)
        #pragma unroll
        for (int pass = 0; pass < 2; pass++) {
            lx2 aF[4], bF[4];
            #pragma unroll
            for (int mi = 0; mi < 4; mi++)
                aF[mi] = *(const lx2*)(As + (wrow * 64 + mi * 16 + ln) * LSTR
                                          + q4 * 32 + pass * 16);
            #pragma unroll
            for (int ni = 0; ni < 4; ni++)
                bF[ni] = *(const lx2*)(Bs + (wcol * 64 + ni * 16 + ln) * LSTR
                                          + q4 * 32 + pass * 16);
            #pragma unroll
            for (int mi = 0; mi < 4; mi++)
                #pragma unroll
                for (int ni = 0; ni < 4; ni++)
                    acc[mi][ni] = __builtin_amdgcn_mfma_f32_16x16x32_fp8_fp8(
                        aF[mi].x, bF[ni].x, acc[mi][ni], 0, 0, 0);
            #pragma unroll
            for (int mi = 0; mi < 4; mi++)
                #pragma unroll
                for (int ni = 0; ni < 4; ni++)
                    acc[mi][ni] = __builtin_amdgcn_mfma_f32_16x16x32_fp8_fp8(
                        aF[mi].y, bF[ni].y, acc[mi][ni], 0, 0, 0);
        }
    }

    // ---- epilogue: C/D col = lane&15 (=j), row = quad*4+reg (=i); /PSCALE ----
    const int i_base = i0 + wrow * 64;
    const int j_base = j0 + wcol * 64;

    float e_j[4];
    #pragma unroll
    for (int ni = 0; ni < 4; ni++) e_j[ni] = e[j_base + ni * 16 + ln];

    #pragma unroll
    for (int mi = 0; mi < 4; mi++) {
        #pragma unroll
        for (int r = 0; r < 4; r++) {
            const int i = i_base + mi * 16 + q4 * 4 + r;
            const uint64_t m  = Lb[(size_t)i * 64 + (j_base >> 6)];
            const uint64_t ms = m >> ln;
            float cs = 0.f, cl = 0.f, el = 0.f;
            #pragma unroll
            for (int ni = 0; ni < 4; ni++) {
                float c = acc[mi][ni][r];
                cs += c;
                if ((ms >> (ni * 16)) & 1ull) { cl += c; el += e_j[ni]; }
            }
            #pragma unroll
            for (int s = 1; s < 16; s <<= 1) {
                cs += __shfl_xor(cs, s);
                cl += __shfl_xor(cl, s);
                el += __shfl_xor(el, s);
            }
            if (ln == 0) {
                atomicAdd(&CS[i], cs * INV_PSCALE);
                atomicAdd(&CL[i], cl * INV_PSCALE);
                atomicAdd(&EL[i], el);
            }
        }
    }
}

// ---------------------------------------------------------------------------
// Kernel 3: final — Etot = sum e; result = sum_i pos/neg
// ---------------------------------------------------------------------------
__global__ __launch_bounds__(256) void final_kernel(
    const float* __restrict__ e, const float* __restrict__ kld,
    const float* __restrict__ CS, const float* __restrict__ CL,
    const float* __restrict__ EL, float* __restrict__ out)
{
    __shared__ float sred[4];
    __shared__ float sEtot;
    const int t = threadIdx.x;
    const int wv = t >> 6, ln = t & 63;

    float s = 0.f;
    for (int j = t; j < BROWS; j += 256) s += e[j];
    #pragma unroll
    for (int off = 32; off > 0; off >>= 1) s += __shfl_down(s, off);
    if (ln == 0) sred[wv] = s;
    __syncthreads();
    if (t == 0) sEtot = sred[0] + sred[1] + sred[2] + sred[3];
    __syncthreads();
    const float Etot = sEtot;
    const float invD = 1.0f / DDIM;

    float rs = 0.f;
    for (int i = t; i < BROWS; i += 256) {
        float el = EL[i], cl = CL[i], cs = CS[i];
        float pos = kld[i] + (el - cl) * invD;
        float neg = (Etot - el - cs + cl) * invD;
        rs += pos / neg;
    }
    __syncthreads();
    #pragma unroll
    for (int off = 32; off > 0; off >>= 1) rs += __shfl_down(rs, off);
    if (ln == 0) sred[wv] = rs;
    __syncthreads();
    if (t == 0) out[0] = sred[0] + sred[1] + sred[2] + sred[3];
}

// ---------------------------------------------------------------------------
extern "C" void kernel_launch(void* const* d_in, const int* in_sizes, int n_in,
                              void* d_out, int out_size, void* d_ws, size_t ws_size,
                              hipStream_t stream)
{
    const float* q = (const float*)d_in[0];
    const float* p = (const float*)d_in[1];
    const float* L = (const float*)d_in[2];
    float* out = (float*)d_out;

    char* ws = (char*)d_ws;
    int*  lq8 = (int*)ws;                                         // 4 MB
    int*  p8  = (int*)(ws + (size_t)BROWS * DDIM);                // 4 MB
    float* e  = (float*)(ws + (size_t)BROWS * DDIM * 2);          // 16 KB
    float* kld = e + BROWS;
    float* CS  = kld + BROWS;
    float* CL  = CS + BROWS;
    float* EL  = CL + BROWS;
    uint64_t* Lb = (uint64_t*)(EL + BROWS);                       // 2 MB

    prep_kernel<<<BROWS, 256, 0, stream>>>(q, p, L, lq8, p8, Lb, e, kld, CS, CL, EL);

    dim3 grid(BROWS / 128, BROWS / 128);
    gemm_epi_kernel<<<grid, 256, 0, stream>>>(
        (const uint8_t*)lq8, (const uint8_t*)p8, Lb, e, CS, CL, EL);

    final_kernel<<<1, 256, 0, stream>>>(e, kld, CS, CL, EL, out);
}

// Round 9
// 182.744 us; speedup vs baseline: 1.2897x; 1.2897x over previous
//
#include <hip/hip_runtime.h>
#include <hip/hip_bf16.h>
#include <stdint.h>

#define BROWS 4096
#define DDIM  1024

typedef __bf16 bf16_t;
typedef __bf16 bf16x8 __attribute__((ext_vector_type(8)));
typedef float  f32x4  __attribute__((ext_vector_type(4)));

#define LDS_STRIDE 68   // bf16 elems: 64 + 4 pad -> measured conflict-free (R4: 0)

__device__ __forceinline__ unsigned short f2bf_bits(float f) {
    union { float f; unsigned int u; } v; v.f = f;
    unsigned int u = v.u;
    unsigned int r = (u + 0x7fffu + ((u >> 16) & 1u)) >> 16;
    return (unsigned short)r;
}

// ---------------------------------------------------------------------------
// Kernel 1: prep — log(q)->bf16, p->bf16, e[row], kl_div[row], zero CS/CL/EL,
//   label bitmask. Bitmask path VECTORIZED: float4 loads + nibble pack +
//   shuffle-OR over 16-lane groups (was 16 scalar loads + 16 ballots).
// ---------------------------------------------------------------------------
__global__ __launch_bounds__(256) void prep_kernel(
    const float* __restrict__ q, const float* __restrict__ p,
    const float* __restrict__ L,
    bf16_t* __restrict__ lqb, bf16_t* __restrict__ pb,
    uint64_t* __restrict__ Lb,
    float* __restrict__ e, float* __restrict__ kld,
    float* __restrict__ CS, float* __restrict__ CL, float* __restrict__ EL)
{
    const int row = blockIdx.x;
    const int t   = threadIdx.x;
    const int wv  = t >> 6, ln = t & 63;
    const int g   = ln & 15;          // position within 16-lane group
    const int wgrp = ln >> 4;         // group index 0..3 within wave

    const float4* q4 = (const float4*)(q + (size_t)row * DDIM);
    const float4* p4 = (const float4*)(p + (size_t)row * DDIM);
    float4 qv = q4[t];
    float4 pv = p4[t];

    float lq0 = __logf(qv.x), lq1 = __logf(qv.y), lq2 = __logf(qv.z), lq3 = __logf(qv.w);
    float lp0 = __logf(pv.x), lp1 = __logf(pv.y), lp2 = __logf(pv.z), lp3 = __logf(pv.w);

    float esum = pv.x * lp0 + pv.y * lp1 + pv.z * lp2 + pv.w * lp3;
    float ksum = pv.x * (lp0 - lq0) + pv.y * (lp1 - lq1)
               + pv.z * (lp2 - lq2) + pv.w * (lp3 - lq3);

    ushort4 uq, up;
    uq.x = f2bf_bits(lq0); uq.y = f2bf_bits(lq1); uq.z = f2bf_bits(lq2); uq.w = f2bf_bits(lq3);
    up.x = f2bf_bits(pv.x); up.y = f2bf_bits(pv.y); up.z = f2bf_bits(pv.z); up.w = f2bf_bits(pv.w);
    ((ushort4*)(lqb + (size_t)row * DDIM))[t] = uq;
    ((ushort4*)(pb  + (size_t)row * DDIM))[t] = up;

    // label bitmask: 4 sweeps x float4; wave wv covers j in [s*1024+wv*256, +256)
    const float4* L4 = (const float4*)(L + (size_t)row * BROWS);
    #pragma unroll
    for (int s = 0; s < 4; s++) {
        float4 lv = L4[s * 256 + t];           // j0 = s*1024 + wv*256 + ln*4
        unsigned int nib = (lv.x != 0.0f ? 1u : 0u)
                         | (lv.y != 0.0f ? 2u : 0u)
                         | (lv.z != 0.0f ? 4u : 0u)
                         | (lv.w != 0.0f ? 8u : 0u);
        unsigned int lo = (g < 8) ? (nib << (4 * g)) : 0u;
        unsigned int hi = (g >= 8) ? (nib << (4 * (g - 8))) : 0u;
        #pragma unroll
        for (int m = 1; m < 16; m <<= 1) {
            lo |= (unsigned int)__shfl_xor((int)lo, m);
            hi |= (unsigned int)__shfl_xor((int)hi, m);
        }
        if (g == 0)
            Lb[(size_t)row * 64 + s * 16 + wv * 4 + wgrp] =
                (uint64_t)lo | ((uint64_t)hi << 32);
    }

    if (t == 0) { CS[row] = 0.f; CL[row] = 0.f; EL[row] = 0.f; }

    #pragma unroll
    for (int off = 32; off > 0; off >>= 1) {
        esum += __shfl_down(esum, off);
        ksum += __shfl_down(ksum, off);
    }
    __shared__ float se[4], sk[4];
    if (ln == 0) { se[wv] = esum; sk[wv] = ksum; }
    __syncthreads();
    if (t == 0) {
        e[row]   = se[0] + se[1] + se[2] + se[3];
        kld[row] = (sk[0] + sk[1] + sk[2] + sk[3]) * (1.0f / DDIM);
    }
}

// ---------------------------------------------------------------------------
// Kernel 2: cross = log_q @ p^T — R4 VERBATIM (measured: 55 us, WRITE 15 MB,
//   0 bank conflicts). Tile 256x128, 512 threads (8 waves of 64x64),
//   K-chunk 64 elems, 1-deep register prefetch, LDS stride 68, 2 blocks/CU.
// ---------------------------------------------------------------------------
__global__ __launch_bounds__(512, 4) void gemm_epi_kernel(
    const bf16_t* __restrict__ Abf,   // log_q [B,D]
    const bf16_t* __restrict__ Bbf,   // p     [B,D]
    const uint64_t* __restrict__ Lb,  // [B, B/64] bitmask
    const float*  __restrict__ e,     // [B]
    float* __restrict__ CS, float* __restrict__ CL, float* __restrict__ EL)
{
    __shared__ __align__(16) bf16_t As[256 * LDS_STRIDE];  // 34 KB
    __shared__ __align__(16) bf16_t Bs[128 * LDS_STRIDE];  // 17 KB

    const int t    = threadIdx.x;
    const int i0   = blockIdx.y * 256;
    const int j0   = blockIdx.x * 128;
    const int wave = t >> 6;
    const int lane = t & 63;
    const int q4   = lane >> 4;
    const int ln   = lane & 15;
    const int wrow = wave & 3;    // 4 i-subtiles
    const int wcol = wave >> 2;   // 2 j-subtiles

    f32x4 acc[4][4];
    #pragma unroll
    for (int a = 0; a < 4; a++)
        #pragma unroll
        for (int b = 0; b < 4; b++)
            acc[a][b] = (f32x4){0.f, 0.f, 0.f, 0.f};

    // staging maps: A chunk 256x64 = 2048 16B-chunks (4/thread);
    //               B chunk 128x64 = 1024 (2/thread). id: row=id>>3, col8=id&7
    const bf16_t* gAp[4]; int lA[4];
    const bf16_t* gBp[2]; int lB[2];
    #pragma unroll
    for (int n = 0; n < 4; n++) {
        const int id = t + n * 512;
        gAp[n] = Abf + (size_t)(i0 + (id >> 3)) * DDIM + (id & 7) * 8;
        lA[n]  = (id >> 3) * LDS_STRIDE + (id & 7) * 8;
    }
    #pragma unroll
    for (int n = 0; n < 2; n++) {
        const int id = t + n * 512;
        gBp[n] = Bbf + (size_t)(j0 + (id >> 3)) * DDIM + (id & 7) * 8;
        lB[n]  = (id >> 3) * LDS_STRIDE + (id & 7) * 8;
    }

    bf16x8 pfA[4], pfB[2];
    #pragma unroll
    for (int n = 0; n < 4; n++) pfA[n] = *(const bf16x8*)(gAp[n]);
    #pragma unroll
    for (int n = 0; n < 2; n++) pfB[n] = *(const bf16x8*)(gBp[n]);

    #pragma unroll 1
    for (int c = 0; c < DDIM / 64; ++c) {
        __syncthreads();   // previous chunk's readers done; LDS reusable
        #pragma unroll
        for (int n = 0; n < 4; n++) *(bf16x8*)(As + lA[n]) = pfA[n];
        #pragma unroll
        for (int n = 0; n < 2; n++) *(bf16x8*)(Bs + lB[n]) = pfB[n];
        __syncthreads();   // chunk c visible

        if (c + 1 < DDIM / 64) {
            const int k = (c + 1) * 64;
            #pragma unroll
            for (int n = 0; n < 4; n++) pfA[n] = *(const bf16x8*)(gAp[n] + k);
            #pragma unroll
            for (int n = 0; n < 2; n++) pfB[n] = *(const bf16x8*)(gBp[n] + k);
        }

        #pragma unroll
        for (int ks = 0; ks < 2; ks++) {
            bf16x8 af[4], bfr[4];
            #pragma unroll
            for (int mi = 0; mi < 4; mi++)
                af[mi] = *(const bf16x8*)(As + (wrow * 64 + mi * 16 + ln) * LDS_STRIDE
                                             + ks * 32 + q4 * 8);
            #pragma unroll
            for (int ni = 0; ni < 4; ni++)
                bfr[ni] = *(const bf16x8*)(Bs + (wcol * 64 + ni * 16 + ln) * LDS_STRIDE
                                              + ks * 32 + q4 * 8);
            #pragma unroll
            for (int mi = 0; mi < 4; mi++)
                #pragma unroll
                for (int ni = 0; ni < 4; ni++)
                    acc[mi][ni] = __builtin_amdgcn_mfma_f32_16x16x32_bf16(
                        af[mi], bfr[ni], acc[mi][ni], 0, 0, 0);
        }
    }

    // ---- epilogue: C/D col = lane&15 (=j), row = quad*4+reg (=i) ----
    const int i_base = i0 + wrow * 64;
    const int j_base = j0 + wcol * 64;

    float e_j[4];
    #pragma unroll
    for (int ni = 0; ni < 4; ni++) e_j[ni] = e[j_base + ni * 16 + ln];

    #pragma unroll
    for (int mi = 0; mi < 4; mi++) {
        #pragma unroll
        for (int r = 0; r < 4; r++) {
            const int i = i_base + mi * 16 + q4 * 4 + r;
            const uint64_t m  = Lb[(size_t)i * 64 + (j_base >> 6)];
            const uint64_t ms = m >> ln;
            float cs = 0.f, cl = 0.f, el = 0.f;
            #pragma unroll
            for (int ni = 0; ni < 4; ni++) {
                float c = acc[mi][ni][r];
                cs += c;
                if ((ms >> (ni * 16)) & 1ull) { cl += c; el += e_j[ni]; }
            }
            #pragma unroll
            for (int s = 1; s < 16; s <<= 1) {
                cs += __shfl_xor(cs, s);
                cl += __shfl_xor(cl, s);
                el += __shfl_xor(el, s);
            }
            if (ln == 0) {
                atomicAdd(&CS[i], cs);
                atomicAdd(&CL[i], cl);
                atomicAdd(&EL[i], el);
            }
        }
    }
}

// ---------------------------------------------------------------------------
// Kernel 3: final — Etot = sum e; result = sum_i pos/neg
// ---------------------------------------------------------------------------
__global__ __launch_bounds__(256) void final_kernel(
    const float* __restrict__ e, const float* __restrict__ kld,
    const float* __restrict__ CS, const float* __restrict__ CL,
    const float* __restrict__ EL, float* __restrict__ out)
{
    __shared__ float sred[4];
    __shared__ float sEtot;
    const int t = threadIdx.x;
    const int wv = t >> 6, ln = t & 63;

    float s = 0.f;
    for (int j = t; j < BROWS; j += 256) s += e[j];
    #pragma unroll
    for (int off = 32; off > 0; off >>= 1) s += __shfl_down(s, off);
    if (ln == 0) sred[wv] = s;
    __syncthreads();
    if (t == 0) sEtot = sred[0] + sred[1] + sred[2] + sred[3];
    __syncthreads();
    const float Etot = sEtot;
    const float invD = 1.0f / DDIM;

    float rs = 0.f;
    for (int i = t; i < BROWS; i += 256) {
        float el = EL[i], cl = CL[i], cs = CS[i];
        float pos = kld[i] + (el - cl) * invD;
        float neg = (Etot - el - cs + cl) * invD;
        rs += pos / neg;
    }
    __syncthreads();
    #pragma unroll
    for (int off = 32; off > 0; off >>= 1) rs += __shfl_down(rs, off);
    if (ln == 0) sred[wv] = rs;
    __syncthreads();
    if (t == 0) out[0] = sred[0] + sred[1] + sred[2] + sred[3];
}

// ---------------------------------------------------------------------------
extern "C" void kernel_launch(void* const* d_in, const int* in_sizes, int n_in,
                              void* d_out, int out_size, void* d_ws, size_t ws_size,
                              hipStream_t stream)
{
    const float* q = (const float*)d_in[0];
    const float* p = (const float*)d_in[1];
    const float* L = (const float*)d_in[2];
    float* out = (float*)d_out;

    char* ws = (char*)d_ws;
    bf16_t* lqb = (bf16_t*)ws;                                    // 8 MB
    bf16_t* pb  = (bf16_t*)(ws + (size_t)BROWS * DDIM * 2);       // 8 MB
    float*  e   = (float*)(ws + (size_t)BROWS * DDIM * 4);        // 16 KB
    float*  kld = e + BROWS;
    float*  CS  = kld + BROWS;
    float*  CL  = CS + BROWS;
    float*  EL  = CL + BROWS;
    uint64_t* Lb = (uint64_t*)(EL + BROWS);                       // 2 MB

    prep_kernel<<<BROWS, 256, 0, stream>>>(q, p, L, lqb, pb, Lb, e, kld, CS, CL, EL);

    dim3 grid(BROWS / 128, BROWS / 256);
    gemm_epi_kernel<<<grid, 512, 0, stream>>>(lqb, pb, Lb, e, CS, CL, EL);

    final_kernel<<<1, 256, 0, stream>>>(e, kld, CS, CL, EL, out);
}

// Round 10
// 180.952 us; speedup vs baseline: 1.3025x; 1.0099x over previous
//
#include <hip/hip_runtime.h>
#include <hip/hip_bf16.h>
#include <stdint.h>

#define BROWS 4096
#define DDIM  1024

typedef __bf16 bf16_t;
typedef __bf16 bf16x8 __attribute__((ext_vector_type(8)));
typedef float  f32x4  __attribute__((ext_vector_type(4)));

#define LDS_STRIDE 68   // bf16 elems: 64 + 4 pad -> measured conflict-free (R4/R9: 0)

__device__ __forceinline__ unsigned short f2bf_bits(float f) {
    union { float f; unsigned int u; } v; v.f = f;
    unsigned int u = v.u;
    unsigned int r = (u + 0x7fffu + ((u >> 16) & 1u)) >> 16;
    return (unsigned short)r;
}

// ---------------------------------------------------------------------------
// Kernel 1: prep — log(q)->bf16, p->bf16, e[row], kl_div[row], zero CS/CL/EL,
//   vectorized label bitmask (float4 + nibble pack + shuffle-OR). R9 verbatim.
// ---------------------------------------------------------------------------
__global__ __launch_bounds__(256) void prep_kernel(
    const float* __restrict__ q, const float* __restrict__ p,
    const float* __restrict__ L,
    bf16_t* __restrict__ lqb, bf16_t* __restrict__ pb,
    uint64_t* __restrict__ Lb,
    float* __restrict__ e, float* __restrict__ kld,
    float* __restrict__ CS, float* __restrict__ CL, float* __restrict__ EL)
{
    const int row = blockIdx.x;
    const int t   = threadIdx.x;
    const int wv  = t >> 6, ln = t & 63;
    const int g   = ln & 15;
    const int wgrp = ln >> 4;

    const float4* q4 = (const float4*)(q + (size_t)row * DDIM);
    const float4* p4 = (const float4*)(p + (size_t)row * DDIM);
    float4 qv = q4[t];
    float4 pv = p4[t];

    float lq0 = __logf(qv.x), lq1 = __logf(qv.y), lq2 = __logf(qv.z), lq3 = __logf(qv.w);
    float lp0 = __logf(pv.x), lp1 = __logf(pv.y), lp2 = __logf(pv.z), lp3 = __logf(pv.w);

    float esum = pv.x * lp0 + pv.y * lp1 + pv.z * lp2 + pv.w * lp3;
    float ksum = pv.x * (lp0 - lq0) + pv.y * (lp1 - lq1)
               + pv.z * (lp2 - lq2) + pv.w * (lp3 - lq3);

    ushort4 uq, up;
    uq.x = f2bf_bits(lq0); uq.y = f2bf_bits(lq1); uq.z = f2bf_bits(lq2); uq.w = f2bf_bits(lq3);
    up.x = f2bf_bits(pv.x); up.y = f2bf_bits(pv.y); up.z = f2bf_bits(pv.z); up.w = f2bf_bits(pv.w);
    ((ushort4*)(lqb + (size_t)row * DDIM))[t] = uq;
    ((ushort4*)(pb  + (size_t)row * DDIM))[t] = up;

    const float4* L4 = (const float4*)(L + (size_t)row * BROWS);
    #pragma unroll
    for (int s = 0; s < 4; s++) {
        float4 lv = L4[s * 256 + t];
        unsigned int nib = (lv.x != 0.0f ? 1u : 0u)
                         | (lv.y != 0.0f ? 2u : 0u)
                         | (lv.z != 0.0f ? 4u : 0u)
                         | (lv.w != 0.0f ? 8u : 0u);
        unsigned int lo = (g < 8) ? (nib << (4 * g)) : 0u;
        unsigned int hi = (g >= 8) ? (nib << (4 * (g - 8))) : 0u;
        #pragma unroll
        for (int m = 1; m < 16; m <<= 1) {
            lo |= (unsigned int)__shfl_xor((int)lo, m);
            hi |= (unsigned int)__shfl_xor((int)hi, m);
        }
        if (g == 0)
            Lb[(size_t)row * 64 + s * 16 + wv * 4 + wgrp] =
                (uint64_t)lo | ((uint64_t)hi << 32);
    }

    if (t == 0) { CS[row] = 0.f; CL[row] = 0.f; EL[row] = 0.f; }

    #pragma unroll
    for (int off = 32; off > 0; off >>= 1) {
        esum += __shfl_down(esum, off);
        ksum += __shfl_down(ksum, off);
    }
    __shared__ float se[4], sk[4];
    if (ln == 0) { se[wv] = esum; sk[wv] = ksum; }
    __syncthreads();
    if (t == 0) {
        e[row]   = se[0] + se[1] + se[2] + se[3];
        kld[row] = (sk[0] + sk[1] + sk[2] + sk[3]) * (1.0f / DDIM);
    }
}

// ---------------------------------------------------------------------------
// Kernel 2: cross = log_q @ p^T — R4/R9 structure (measured 55.6 us, WRITE
//   15 MB, 0 conflicts) + XCD-AWARE SWIZZLE: 1D grid of 512; patch = b&7
//   (round-robin XCD residue) selects an 8x8 block patch of the 16x32 tile
//   grid, so each XCD's resident blocks share 8 i-tiles + 8 j-tiles
//   (6 MB distinct vs 16 MB unswizzled) -> higher L2 hit on staging.
// ---------------------------------------------------------------------------
__global__ __launch_bounds__(512, 4) void gemm_epi_kernel(
    const bf16_t* __restrict__ Abf,   // log_q [B,D]
    const bf16_t* __restrict__ Bbf,   // p     [B,D]
    const uint64_t* __restrict__ Lb,  // [B, B/64] bitmask
    const float*  __restrict__ e,     // [B]
    float* __restrict__ CS, float* __restrict__ CL, float* __restrict__ EL)
{
    __shared__ __align__(16) bf16_t As[256 * LDS_STRIDE];  // 34 KB
    __shared__ __align__(16) bf16_t Bs[128 * LDS_STRIDE];  // 17 KB

    const int t    = threadIdx.x;
    // XCD swizzle: b -> (i_idx 0..15, j_idx 0..31), patch-of-8x8 per XCD
    const int b     = blockIdx.x;
    const int xcd   = b & 7;
    const int s     = b >> 3;                      // 0..63 within patch
    const int i_idx = (xcd >> 2) * 8 + (s >> 3);   // 0..15
    const int j_idx = (xcd & 3) * 8 + (s & 7);     // 0..31
    const int i0   = i_idx * 256;
    const int j0   = j_idx * 128;
    const int wave = t >> 6;
    const int lane = t & 63;
    const int q4   = lane >> 4;
    const int ln   = lane & 15;
    const int wrow = wave & 3;    // 4 i-subtiles
    const int wcol = wave >> 2;   // 2 j-subtiles

    f32x4 acc[4][4];
    #pragma unroll
    for (int a = 0; a < 4; a++)
        #pragma unroll
        for (int bq = 0; bq < 4; bq++)
            acc[a][bq] = (f32x4){0.f, 0.f, 0.f, 0.f};

    // staging maps: A chunk 256x64 = 2048 16B-chunks (4/thread);
    //               B chunk 128x64 = 1024 (2/thread). id: row=id>>3, col8=id&7
    const bf16_t* gAp[4]; int lA[4];
    const bf16_t* gBp[2]; int lB[2];
    #pragma unroll
    for (int n = 0; n < 4; n++) {
        const int id = t + n * 512;
        gAp[n] = Abf + (size_t)(i0 + (id >> 3)) * DDIM + (id & 7) * 8;
        lA[n]  = (id >> 3) * LDS_STRIDE + (id & 7) * 8;
    }
    #pragma unroll
    for (int n = 0; n < 2; n++) {
        const int id = t + n * 512;
        gBp[n] = Bbf + (size_t)(j0 + (id >> 3)) * DDIM + (id & 7) * 8;
        lB[n]  = (id >> 3) * LDS_STRIDE + (id & 7) * 8;
    }

    bf16x8 pfA[4], pfB[2];
    #pragma unroll
    for (int n = 0; n < 4; n++) pfA[n] = *(const bf16x8*)(gAp[n]);
    #pragma unroll
    for (int n = 0; n < 2; n++) pfB[n] = *(const bf16x8*)(gBp[n]);

    #pragma unroll 1
    for (int c = 0; c < DDIM / 64; ++c) {
        __syncthreads();   // previous chunk's readers done; LDS reusable
        #pragma unroll
        for (int n = 0; n < 4; n++) *(bf16x8*)(As + lA[n]) = pfA[n];
        #pragma unroll
        for (int n = 0; n < 2; n++) *(bf16x8*)(Bs + lB[n]) = pfB[n];
        __syncthreads();   // chunk c visible

        if (c + 1 < DDIM / 64) {
            const int k = (c + 1) * 64;
            #pragma unroll
            for (int n = 0; n < 4; n++) pfA[n] = *(const bf16x8*)(gAp[n] + k);
            #pragma unroll
            for (int n = 0; n < 2; n++) pfB[n] = *(const bf16x8*)(gBp[n] + k);
        }

        #pragma unroll
        for (int ks = 0; ks < 2; ks++) {
            bf16x8 af[4], bfr[4];
            #pragma unroll
            for (int mi = 0; mi < 4; mi++)
                af[mi] = *(const bf16x8*)(As + (wrow * 64 + mi * 16 + ln) * LDS_STRIDE
                                             + ks * 32 + q4 * 8);
            #pragma unroll
            for (int ni = 0; ni < 4; ni++)
                bfr[ni] = *(const bf16x8*)(Bs + (wcol * 64 + ni * 16 + ln) * LDS_STRIDE
                                              + ks * 32 + q4 * 8);
            #pragma unroll
            for (int mi = 0; mi < 4; mi++)
                #pragma unroll
                for (int ni = 0; ni < 4; ni++)
                    acc[mi][ni] = __builtin_amdgcn_mfma_f32_16x16x32_bf16(
                        af[mi], bfr[ni], acc[mi][ni], 0, 0, 0);
        }
    }

    // ---- epilogue: C/D col = lane&15 (=j), row = quad*4+reg (=i) ----
    const int i_base = i0 + wrow * 64;
    const int j_base = j0 + wcol * 64;

    float e_j[4];
    #pragma unroll
    for (int ni = 0; ni < 4; ni++) e_j[ni] = e[j_base + ni * 16 + ln];

    #pragma unroll
    for (int mi = 0; mi < 4; mi++) {
        #pragma unroll
        for (int r = 0; r < 4; r++) {
            const int i = i_base + mi * 16 + q4 * 4 + r;
            const uint64_t m  = Lb[(size_t)i * 64 + (j_base >> 6)];
            const uint64_t ms = m >> ln;
            float cs = 0.f, cl = 0.f, el = 0.f;
            #pragma unroll
            for (int ni = 0; ni < 4; ni++) {
                float c = acc[mi][ni][r];
                cs += c;
                if ((ms >> (ni * 16)) & 1ull) { cl += c; el += e_j[ni]; }
            }
            #pragma unroll
            for (int sft = 1; sft < 16; sft <<= 1) {
                cs += __shfl_xor(cs, sft);
                cl += __shfl_xor(cl, sft);
                el += __shfl_xor(el, sft);
            }
            if (ln == 0) {
                atomicAdd(&CS[i], cs);
                atomicAdd(&CL[i], cl);
                atomicAdd(&EL[i], el);
            }
        }
    }
}

// ---------------------------------------------------------------------------
// Kernel 3: final — Etot = sum e; result = sum_i pos/neg
// ---------------------------------------------------------------------------
__global__ __launch_bounds__(256) void final_kernel(
    const float* __restrict__ e, const float* __restrict__ kld,
    const float* __restrict__ CS, const float* __restrict__ CL,
    const float* __restrict__ EL, float* __restrict__ out)
{
    __shared__ float sred[4];
    __shared__ float sEtot;
    const int t = threadIdx.x;
    const int wv = t >> 6, ln = t & 63;

    float s = 0.f;
    for (int j = t; j < BROWS; j += 256) s += e[j];
    #pragma unroll
    for (int off = 32; off > 0; off >>= 1) s += __shfl_down(s, off);
    if (ln == 0) sred[wv] = s;
    __syncthreads();
    if (t == 0) sEtot = sred[0] + sred[1] + sred[2] + sred[3];
    __syncthreads();
    const float Etot = sEtot;
    const float invD = 1.0f / DDIM;

    float rs = 0.f;
    for (int i = t; i < BROWS; i += 256) {
        float el = EL[i], cl = CL[i], cs = CS[i];
        float pos = kld[i] + (el - cl) * invD;
        float neg = (Etot - el - cs + cl) * invD;
        rs += pos / neg;
    }
    __syncthreads();
    #pragma unroll
    for (int off = 32; off > 0; off >>= 1) rs += __shfl_down(rs, off);
    if (ln == 0) sred[wv] = rs;
    __syncthreads();
    if (t == 0) out[0] = sred[0] + sred[1] + sred[2] + sred[3];
}

// ---------------------------------------------------------------------------
extern "C" void kernel_launch(void* const* d_in, const int* in_sizes, int n_in,
                              void* d_out, int out_size, void* d_ws, size_t ws_size,
                              hipStream_t stream)
{
    const float* q = (const float*)d_in[0];
    const float* p = (const float*)d_in[1];
    const float* L = (const float*)d_in[2];
    float* out = (float*)d_out;

    char* ws = (char*)d_ws;
    bf16_t* lqb = (bf16_t*)ws;                                    // 8 MB
    bf16_t* pb  = (bf16_t*)(ws + (size_t)BROWS * DDIM * 2);       // 8 MB
    float*  e   = (float*)(ws + (size_t)BROWS * DDIM * 4);        // 16 KB
    float*  kld = e + BROWS;
    float*  CS  = kld + BROWS;
    float*  CL  = CS + BROWS;
    float*  EL  = CL + BROWS;
    uint64_t* Lb = (uint64_t*)(EL + BROWS);                       // 2 MB

    prep_kernel<<<BROWS, 256, 0, stream>>>(q, p, L, lqb, pb, Lb, e, kld, CS, CL, EL);

    gemm_epi_kernel<<<512, 512, 0, stream>>>(lqb, pb, Lb, e, CS, CL, EL);

    final_kernel<<<1, 256, 0, stream>>>(e, kld, CS, CL, EL, out);
}

// Round 11
// 178.975 us; speedup vs baseline: 1.3168x; 1.0110x over previous
//
#include <hip/hip_runtime.h>
#include <hip/hip_bf16.h>
#include <stdint.h>

#define BROWS 4096
#define DDIM  1024

typedef __bf16 bf16_t;
typedef __bf16 bf16x8 __attribute__((ext_vector_type(8)));
typedef float  f32x4  __attribute__((ext_vector_type(4)));

#define LDS_STRIDE 68   // bf16 elems: 64 + 4 pad -> measured conflict-free (R4/R9/R10: 0)

// Lb bit layout (ballot-native): word w = (j>>8)*4 + (j&3), bit b = (j&255)>>2.
// Chosen so prep emits words straight from __ballot with no cross-lane packing.

__device__ __forceinline__ unsigned short f2bf_bits(float f) {
    union { float f; unsigned int u; } v; v.f = f;
    unsigned int u = v.u;
    unsigned int r = (u + 0x7fffu + ((u >> 16) & 1u)) >> 16;
    return (unsigned short)r;
}

// ---------------------------------------------------------------------------
// Kernel 1: prep — log(q)->bf16, p->bf16, e[row], kl_div[row], zero CS/CL/EL,
//   label bitmask via 4 BALLOTS per sweep (no shuffles — ballot-native layout).
// ---------------------------------------------------------------------------
__global__ __launch_bounds__(256) void prep_kernel(
    const float* __restrict__ q, const float* __restrict__ p,
    const float* __restrict__ L,
    bf16_t* __restrict__ lqb, bf16_t* __restrict__ pb,
    uint64_t* __restrict__ Lb,
    float* __restrict__ e, float* __restrict__ kld,
    float* __restrict__ CS, float* __restrict__ CL, float* __restrict__ EL)
{
    const int row = blockIdx.x;
    const int t   = threadIdx.x;
    const int wv  = t >> 6, ln = t & 63;

    const float4* q4 = (const float4*)(q + (size_t)row * DDIM);
    const float4* p4 = (const float4*)(p + (size_t)row * DDIM);
    float4 qv = q4[t];
    float4 pv = p4[t];

    float lq0 = __logf(qv.x), lq1 = __logf(qv.y), lq2 = __logf(qv.z), lq3 = __logf(qv.w);
    float lp0 = __logf(pv.x), lp1 = __logf(pv.y), lp2 = __logf(pv.z), lp3 = __logf(pv.w);

    float esum = pv.x * lp0 + pv.y * lp1 + pv.z * lp2 + pv.w * lp3;
    float ksum = pv.x * (lp0 - lq0) + pv.y * (lp1 - lq1)
               + pv.z * (lp2 - lq2) + pv.w * (lp3 - lq3);

    ushort4 uq, up;
    uq.x = f2bf_bits(lq0); uq.y = f2bf_bits(lq1); uq.z = f2bf_bits(lq2); uq.w = f2bf_bits(lq3);
    up.x = f2bf_bits(pv.x); up.y = f2bf_bits(pv.y); up.z = f2bf_bits(pv.z); up.w = f2bf_bits(pv.w);
    ((ushort4*)(lqb + (size_t)row * DDIM))[t] = uq;
    ((ushort4*)(pb  + (size_t)row * DDIM))[t] = up;

    // label bitmask, ballot-native: thread t sweep s covers j = s*1024 + t*4 + comp.
    // Word (s*4+wv)*4 + comp, bit ln  ==  layout {w=(j>>8)*4+(j&3), b=(j&255)>>2}.
    const float4* L4 = (const float4*)(L + (size_t)row * BROWS);
    #pragma unroll
    for (int s = 0; s < 4; s++) {
        float4 lv = L4[s * 256 + t];
        unsigned long long b0 = __ballot(lv.x != 0.0f);
        unsigned long long b1 = __ballot(lv.y != 0.0f);
        unsigned long long b2 = __ballot(lv.z != 0.0f);
        unsigned long long b3 = __ballot(lv.w != 0.0f);
        if (ln < 4) {
            unsigned long long w = (ln == 0) ? b0 : (ln == 1) ? b1 : (ln == 2) ? b2 : b3;
            Lb[(size_t)row * 64 + (s * 4 + wv) * 4 + ln] = w;
        }
    }

    if (t == 0) { CS[row] = 0.f; CL[row] = 0.f; EL[row] = 0.f; }

    #pragma unroll
    for (int off = 32; off > 0; off >>= 1) {
        esum += __shfl_down(esum, off);
        ksum += __shfl_down(ksum, off);
    }
    __shared__ float se[4], sk[4];
    if (ln == 0) { se[wv] = esum; sk[wv] = ksum; }
    __syncthreads();
    if (t == 0) {
        e[row]   = se[0] + se[1] + se[2] + se[3];
        kld[row] = (sk[0] + sk[1] + sk[2] + sk[3]) * (1.0f / DDIM);
    }
}

// ---------------------------------------------------------------------------
// Kernel 2: cross = log_q @ p^T — R10 verbatim K-loop (measured 54.4 us,
//   WRITE 15 MB, 0 conflicts, FETCH 27.5 MB w/ XCD swizzle). Epilogue bit
//   extraction adapted to the ballot-native Lb layout (same op count).
// ---------------------------------------------------------------------------
__global__ __launch_bounds__(512, 4) void gemm_epi_kernel(
    const bf16_t* __restrict__ Abf,   // log_q [B,D]
    const bf16_t* __restrict__ Bbf,   // p     [B,D]
    const uint64_t* __restrict__ Lb,  // [B,64] ballot-native bitmask
    const float*  __restrict__ e,     // [B]
    float* __restrict__ CS, float* __restrict__ CL, float* __restrict__ EL)
{
    __shared__ __align__(16) bf16_t As[256 * LDS_STRIDE];  // 34 KB
    __shared__ __align__(16) bf16_t Bs[128 * LDS_STRIDE];  // 17 KB

    const int t    = threadIdx.x;
    // XCD swizzle: b -> (i_idx 0..15, j_idx 0..31), patch-of-8x8 per XCD
    const int b     = blockIdx.x;
    const int xcd   = b & 7;
    const int s     = b >> 3;                      // 0..63 within patch
    const int i_idx = (xcd >> 2) * 8 + (s >> 3);   // 0..15
    const int j_idx = (xcd & 3) * 8 + (s & 7);     // 0..31
    const int i0   = i_idx * 256;
    const int j0   = j_idx * 128;
    const int wave = t >> 6;
    const int lane = t & 63;
    const int q4   = lane >> 4;
    const int ln   = lane & 15;
    const int wrow = wave & 3;    // 4 i-subtiles
    const int wcol = wave >> 2;   // 2 j-subtiles

    f32x4 acc[4][4];
    #pragma unroll
    for (int a = 0; a < 4; a++)
        #pragma unroll
        for (int bq = 0; bq < 4; bq++)
            acc[a][bq] = (f32x4){0.f, 0.f, 0.f, 0.f};

    const bf16_t* gAp[4]; int lA[4];
    const bf16_t* gBp[2]; int lB[2];
    #pragma unroll
    for (int n = 0; n < 4; n++) {
        const int id = t + n * 512;
        gAp[n] = Abf + (size_t)(i0 + (id >> 3)) * DDIM + (id & 7) * 8;
        lA[n]  = (id >> 3) * LDS_STRIDE + (id & 7) * 8;
    }
    #pragma unroll
    for (int n = 0; n < 2; n++) {
        const int id = t + n * 512;
        gBp[n] = Bbf + (size_t)(j0 + (id >> 3)) * DDIM + (id & 7) * 8;
        lB[n]  = (id >> 3) * LDS_STRIDE + (id & 7) * 8;
    }

    bf16x8 pfA[4], pfB[2];
    #pragma unroll
    for (int n = 0; n < 4; n++) pfA[n] = *(const bf16x8*)(gAp[n]);
    #pragma unroll
    for (int n = 0; n < 2; n++) pfB[n] = *(const bf16x8*)(gBp[n]);

    #pragma unroll 1
    for (int c = 0; c < DDIM / 64; ++c) {
        __syncthreads();
        #pragma unroll
        for (int n = 0; n < 4; n++) *(bf16x8*)(As + lA[n]) = pfA[n];
        #pragma unroll
        for (int n = 0; n < 2; n++) *(bf16x8*)(Bs + lB[n]) = pfB[n];
        __syncthreads();

        if (c + 1 < DDIM / 64) {
            const int k = (c + 1) * 64;
            #pragma unroll
            for (int n = 0; n < 4; n++) pfA[n] = *(const bf16x8*)(gAp[n] + k);
            #pragma unroll
            for (int n = 0; n < 2; n++) pfB[n] = *(const bf16x8*)(gBp[n] + k);
        }

        #pragma unroll
        for (int ks = 0; ks < 2; ks++) {
            bf16x8 af[4], bfr[4];
            #pragma unroll
            for (int mi = 0; mi < 4; mi++)
                af[mi] = *(const bf16x8*)(As + (wrow * 64 + mi * 16 + ln) * LDS_STRIDE
                                             + ks * 32 + q4 * 8);
            #pragma unroll
            for (int ni = 0; ni < 4; ni++)
                bfr[ni] = *(const bf16x8*)(Bs + (wcol * 64 + ni * 16 + ln) * LDS_STRIDE
                                              + ks * 32 + q4 * 8);
            #pragma unroll
            for (int mi = 0; mi < 4; mi++)
                #pragma unroll
                for (int ni = 0; ni < 4; ni++)
                    acc[mi][ni] = __builtin_amdgcn_mfma_f32_16x16x32_bf16(
                        af[mi], bfr[ni], acc[mi][ni], 0, 0, 0);
        }
    }

    // ---- epilogue: C/D col = lane&15 (=j), row = quad*4+reg (=i) ----
    // Ballot-native Lb: word = (j_base>>8)*4 + (ln&3); within it, the bit for
    // column j_base+ni*16+ln sits at ((j_base&255)>>2) + (ln>>2) + ni*4.
    const int i_base = i0 + wrow * 64;
    const int j_base = j0 + wcol * 64;
    const int wbase  = (j_base >> 8) * 4 + (ln & 3);
    const int bshift = ((j_base & 255) >> 2) + (ln >> 2);

    float e_j[4];
    #pragma unroll
    for (int ni = 0; ni < 4; ni++) e_j[ni] = e[j_base + ni * 16 + ln];

    #pragma unroll
    for (int mi = 0; mi < 4; mi++) {
        #pragma unroll
        for (int r = 0; r < 4; r++) {
            const int i = i_base + mi * 16 + q4 * 4 + r;
            const uint64_t m  = Lb[(size_t)i * 64 + wbase];
            const uint64_t ms = m >> bshift;   // bit ni*4 selects column ni*16+ln
            float cs = 0.f, cl = 0.f, el = 0.f;
            #pragma unroll
            for (int ni = 0; ni < 4; ni++) {
                float c = acc[mi][ni][r];
                cs += c;
                if ((ms >> (ni * 4)) & 1ull) { cl += c; el += e_j[ni]; }
            }
            #pragma unroll
            for (int sft = 1; sft < 16; sft <<= 1) {
                cs += __shfl_xor(cs, sft);
                cl += __shfl_xor(cl, sft);
                el += __shfl_xor(el, sft);
            }
            if (ln == 0) {
                atomicAdd(&CS[i], cs);
                atomicAdd(&CL[i], cl);
                atomicAdd(&EL[i], el);
            }
        }
    }
}

// ---------------------------------------------------------------------------
// Kernel 3: final — Etot = sum e; result = sum_i pos/neg
// ---------------------------------------------------------------------------
__global__ __launch_bounds__(256) void final_kernel(
    const float* __restrict__ e, const float* __restrict__ kld,
    const float* __restrict__ CS, const float* __restrict__ CL,
    const float* __restrict__ EL, float* __restrict__ out)
{
    __shared__ float sred[4];
    __shared__ float sEtot;
    const int t = threadIdx.x;
    const int wv = t >> 6, ln = t & 63;

    float s = 0.f;
    for (int j = t; j < BROWS; j += 256) s += e[j];
    #pragma unroll
    for (int off = 32; off > 0; off >>= 1) s += __shfl_down(s, off);
    if (ln == 0) sred[wv] = s;
    __syncthreads();
    if (t == 0) sEtot = sred[0] + sred[1] + sred[2] + sred[3];
    __syncthreads();
    const float Etot = sEtot;
    const float invD = 1.0f / DDIM;

    float rs = 0.f;
    for (int i = t; i < BROWS; i += 256) {
        float el = EL[i], cl = CL[i], cs = CS[i];
        float pos = kld[i] + (el - cl) * invD;
        float neg = (Etot - el - cs + cl) * invD;
        rs += pos / neg;
    }
    __syncthreads();
    #pragma unroll
    for (int off = 32; off > 0; off >>= 1) rs += __shfl_down(rs, off);
    if (ln == 0) sred[wv] = rs;
    __syncthreads();
    if (t == 0) out[0] = sred[0] + sred[1] + sred[2] + sred[3];
}

// ---------------------------------------------------------------------------
extern "C" void kernel_launch(void* const* d_in, const int* in_sizes, int n_in,
                              void* d_out, int out_size, void* d_ws, size_t ws_size,
                              hipStream_t stream)
{
    const float* q = (const float*)d_in[0];
    const float* p = (const float*)d_in[1];
    const float* L = (const float*)d_in[2];
    float* out = (float*)d_out;

    char* ws = (char*)d_ws;
    bf16_t* lqb = (bf16_t*)ws;                                    // 8 MB
    bf16_t* pb  = (bf16_t*)(ws + (size_t)BROWS * DDIM * 2);       // 8 MB
    float*  e   = (float*)(ws + (size_t)BROWS * DDIM * 4);        // 16 KB
    float*  kld = e + BROWS;
    float*  CS  = kld + BROWS;
    float*  CL  = CS + BROWS;
    float*  EL  = CL + BROWS;
    uint64_t* Lb = (uint64_t*)(EL + BROWS);                       // 2 MB

    prep_kernel<<<BROWS, 256, 0, stream>>>(q, p, L, lqb, pb, Lb, e, kld, CS, CL, EL);

    gemm_epi_kernel<<<512, 512, 0, stream>>>(lqb, pb, Lb, e, CS, CL, EL);

    final_kernel<<<1, 256, 0, stream>>>(e, kld, CS, CL, EL, out);
}